// Round 2
// baseline (955.098 us; speedup 1.0000x reference)
//
#include <hip/hip_runtime.h>
#include <cstdint>
#include <cstddef>

typedef unsigned short u16;
typedef __attribute__((ext_vector_type(8))) short  bf16x8;  // 8 bf16 = 4 VGPRs
typedef __attribute__((ext_vector_type(4))) float  f32x4;   // MFMA C/D frag
typedef __attribute__((ext_vector_type(4))) unsigned short u16x4;

// ---------- helpers ----------
__device__ __forceinline__ u16 f2bf(float f) {
    unsigned u = __float_as_uint(f);
    unsigned r = (u + 0x7FFFu + ((u >> 16) & 1u)) >> 16;
    return (u16)r;
}

__device__ __forceinline__ void async_lds16(const u16* g, u16* l) {
    __builtin_amdgcn_global_load_lds(
        (const __attribute__((address_space(1))) unsigned int*)g,
        (__attribute__((address_space(3))) unsigned int*)l,
        16, 0, 0);
}

// ---------- f32 -> bf16 convert, dense 16B-in/8B-out per lane, grid-stride ----------
// (R2: replaced the 32B-stride two-float4 pattern with the textbook-dense one as
// insurance against cvt3 being the hidden ~330us dispatch; n* in float4 units.)
__global__ __launch_bounds__(256) void cvt3_kernel(const float* __restrict__ s0, u16* __restrict__ d0, int n0,
                                                   const float* __restrict__ s1, u16* __restrict__ d1, int n1,
                                                   const float* __restrict__ s2, u16* __restrict__ d2, int n2) {
    const int total = n0 + n1 + n2;
    for (int i = blockIdx.x * 256 + threadIdx.x; i < total; i += gridDim.x * 256) {
        const float* s; u16* d; int j = i;
        if (j < n0)            { s = s0; d = d0; }
        else if (j < n0 + n1)  { s = s1; d = d1; j -= n0; }
        else                   { s = s2; d = d2; j -= n0 + n1; }
        float4 a = ((const float4*)s)[j];
        u16x4 o;
        o[0] = f2bf(a.x); o[1] = f2bf(a.y); o[2] = f2bf(a.z); o[3] = f2bf(a.w);
        ((u16x4*)d)[j] = o;
    }
}

// ---------- 256x256, BK=64, 8-wave, pipelined-lgkm 4-phase bf16 GEMM, C = A @ B^T ----
// R2 change vs R1: each phase's ds_reads are issued during the PREVIOUS phase's MFMA
// cluster (ping-pong frag regs afA/afB, bfA/bfB), so the lgkmcnt(0) at phase entry
// finds them complete -> LDS service time hides under MFMA (T4 applied to lgkm).
// Barriers reduced to 2 per K-tile; ordering proof:
//  - bar@P2 (before STAGE t+2,k0): every wave's P0/P1-entry lgkmcnt(0) (last k0-frag
//    readers) precedes its bar2 arrival -> overwrite of current-buffer k0 is ordered.
//  - vmcnt(4)+bar@P3: retires (t+1,k0)+(t+1,k1) loads wave-locally; the barrier makes
//    all waves' staged data visible before any wave issues next-tile P0 ds_reads.
//  - STAGE(t+1,k1)@P0 targets the other buffer; its last readers (P2/P3 of t-1)
//    completed before bar@P3(t-1).
//  - vmcnt never 0 in the loop; steady state: enter t with (t+1,k0)[4] in flight,
//    +4 @P0, +4 @P2, vmcnt(4) @P3. Tail wraps mod NT (even -> parity preserved).
#define KHSZ (256 * 32)   // u16 elems in one [256][32] K-half block (16 KB)

template<bool GELU, typename OutT>
__global__ __launch_bounds__(512, 2) void gemm256(const u16* __restrict__ A,
                                                  const u16* __restrict__ B,
                                                  OutT* __restrict__ C,
                                                  int K, int lda, int ldb, int ldc) {
    __shared__ __align__(16) u16 sA[2][2][KHSZ];  // 64 KB
    __shared__ __align__(16) u16 sB[2][2][KHSZ];  // 64 KB

    const int tid  = threadIdx.x;
    const int wave = tid >> 6;
    const int lane = tid & 63;
    const int quad = lane >> 4;
    const int r16  = lane & 15;

    // XCD-chunked bijective swizzle (T1); nwg % 8 == 0 for all our launches
    const int nwg = gridDim.x * gridDim.y;
    int lin = blockIdx.y * gridDim.x + blockIdx.x;
    lin = (lin & 7) * (nwg >> 3) + (lin >> 3);
    const int n0 = (lin % gridDim.x) * 256;
    const int m0 = (lin / gridDim.x) * 256;

    const int wm = (wave >> 2) * 128;   // 2 waves tile M
    const int wn = (wave & 3) * 64;     // 4 waves tile N

    // staging map: 512 threads x 16B = 128 rows (4 thr/row) per issue, 2 issues/half-tile
    const int srow = tid >> 2;                              // 0..127
    const int scol = ((tid & 3) ^ ((srow >> 1) & 3)) * 8;   // pre-swizzled global granule
    const int ld0  = (wave * 16) * 32;                      // wave-uniform LDS dest (u16)
    const int ld1  = (128 + wave * 16) * 32;

    const u16* gA0 = A + (size_t)(m0 + srow) * lda + scol;
    const u16* gA1 = A + (size_t)(m0 + 128 + srow) * lda + scol;
    const u16* gB0 = B + (size_t)(n0 + srow) * ldb + scol;
    const u16* gB1 = B + (size_t)(n0 + 128 + srow) * ldb + scol;

#define STAGE_A(t, kh) { const int ko_ = (t) * 64 + (kh) * 32; u16* d_ = &sA[(t) & 1][kh][0]; \
        async_lds16(gA0 + ko_, d_ + ld0); async_lds16(gA1 + ko_, d_ + ld1); }
#define STAGE_B(t, kh) { const int ko_ = (t) * 64 + (kh) * 32; u16* d_ = &sB[(t) & 1][kh][0]; \
        async_lds16(gB0 + ko_, d_ + ld0); async_lds16(gB1 + ko_, d_ + ld1); }

    // loop-invariant per-lane fragment offsets into a [256][32] half-K block
    int oA[8], oB[4];
#pragma unroll
    for (int i = 0; i < 8; i++) {
        int ra = wm + i * 16 + r16;
        oA[i] = ra * 32 + ((quad ^ ((ra >> 1) & 3)) << 3);
    }
#pragma unroll
    for (int i = 0; i < 4; i++) {
        int rb = wn + i * 16 + r16;
        oB[i] = rb * 32 + ((quad ^ ((rb >> 1) & 3)) << 3);
    }

    f32x4 acc[8][4] = {};
    const int NT = K / 64;   // 96 (GEMM1) / 64 (GEMM2); even by construction

#define LGKM0 asm volatile("s_waitcnt lgkmcnt(0)" ::: "memory"); __builtin_amdgcn_sched_barrier(0)
#define SBAR  __builtin_amdgcn_sched_barrier(0)
#define MFMA_Q(mbase, AF, BF) \
    __builtin_amdgcn_s_setprio(1); \
    _Pragma("unroll") \
    for (int mi_ = 0; mi_ < 4; mi_++) \
        _Pragma("unroll") \
        for (int ni_ = 0; ni_ < 4; ni_++) \
            acc[(mbase) + mi_][ni_] = __builtin_amdgcn_mfma_f32_16x16x32_bf16( \
                AF[mi_], BF[ni_], acc[(mbase) + mi_][ni_], 0, 0, 0); \
    __builtin_amdgcn_s_setprio(0); \
    __builtin_amdgcn_sched_barrier(0)

    bf16x8 afA[4], afB[4], bfA[4], bfB[4];

    // prologue: tile0 fully staged, tile1 k0 in flight, P0 reads issued
    STAGE_A(0, 0); STAGE_B(0, 0);
    STAGE_A(0, 1); STAGE_B(0, 1);
    STAGE_A(1, 0); STAGE_B(1, 0);
    asm volatile("s_waitcnt vmcnt(4)" ::: "memory");
    __builtin_amdgcn_s_barrier();
    SBAR;
    {
        const u16* Ak0 = &sA[0][0][0];
        const u16* Bk0 = &sB[0][0][0];
#pragma unroll
        for (int i = 0; i < 4; i++) {
            afA[i] = *(const bf16x8*)&Ak0[oA[i]];
            bfA[i] = *(const bf16x8*)&Bk0[oB[i]];
        }
    }

    for (int t = 0; t < NT; ++t) {
        const u16* Ak0 = &sA[t & 1][0][0];
        const u16* Ak1 = &sA[t & 1][1][0];
        const u16* Bk1 = &sB[t & 1][1][0];
        const u16* nAk0 = &sA[(t + 1) & 1][0][0];
        const u16* nBk0 = &sB[(t + 1) & 1][0][0];
        const int tn  = (t + 1 < NT) ? t + 1 : t + 1 - NT;  // parity-preserving wraps
        const int tn2 = (t + 2 < NT) ? t + 2 : t + 2 - NT;

        // ---- P0: MFMA rows0-3 x k0 (afA,bfA); issue afB <- A(4-7,k0); stage (t+1,k1) ----
        LGKM0;
        STAGE_A(tn, 1); STAGE_B(tn, 1);
#pragma unroll
        for (int i = 0; i < 4; i++) afB[i] = *(const bf16x8*)&Ak0[oA[4 + i]];
        SBAR;
        MFMA_Q(0, afA, bfA);

        // ---- P1: MFMA rows4-7 x k0 (afB,bfA); issue afA <- A(0-3,k1), bfB <- B(k1) ----
        LGKM0;
#pragma unroll
        for (int i = 0; i < 4; i++) {
            afA[i] = *(const bf16x8*)&Ak1[oA[i]];
            bfB[i] = *(const bf16x8*)&Bk1[oB[i]];
        }
        SBAR;
        MFMA_Q(4, afB, bfA);

        // ---- P2: barrier (k0 readers done) -> stage (t+2,k0); MFMA rows0-3 x k1 ----
        __builtin_amdgcn_s_barrier();
        LGKM0;
        STAGE_A(tn2, 0); STAGE_B(tn2, 0);
#pragma unroll
        for (int i = 0; i < 4; i++) afB[i] = *(const bf16x8*)&Ak1[oA[4 + i]];
        SBAR;
        MFMA_Q(0, afA, bfB);

        // ---- P3: counted vmcnt + barrier (t+1 staged & visible); MFMA rows4-7 x k1;
        //          issue next-tile P0 reads ----
        LGKM0;
        asm volatile("s_waitcnt vmcnt(4)" ::: "memory");
        __builtin_amdgcn_s_barrier();
        SBAR;
#pragma unroll
        for (int i = 0; i < 4; i++) {
            afA[i] = *(const bf16x8*)&nAk0[oA[i]];
            bfA[i] = *(const bf16x8*)&nBk0[oB[i]];
        }
        SBAR;
        MFMA_Q(4, afB, bfB);
    }

    // epilogue: C/D layout col = lane&15, row = quad*4 + reg  [m89-verified]
#pragma unroll
    for (int mi = 0; mi < 8; mi++) {
#pragma unroll
        for (int r = 0; r < 4; r++) {
            size_t rowoff = (size_t)(m0 + wm + mi * 16 + quad * 4 + r) * ldc;
#pragma unroll
            for (int ni = 0; ni < 4; ni++) {
                int col = n0 + wn + ni * 16 + r16;
                float v = acc[mi][ni][r];
                if constexpr (GELU)
                    v = 0.5f * v * (1.0f + erff(v * 0.70710678118654752f));
                if constexpr (sizeof(OutT) == 2)
                    ((u16*)C)[rowoff + col] = f2bf(v);
                else
                    ((float*)C)[rowoff + col] = v;
            }
        }
    }
}

// ---------- launch ----------
extern "C" void kernel_launch(void* const* d_in, const int* in_sizes, int n_in,
                              void* d_out, int out_size, void* d_ws, size_t ws_size,
                              hipStream_t stream) {
    const int T   = 8192;
    const int DIN = 6144;
    const int DFF = 4096;
    const int DM  = 1024;

    const float* x  = (const float*)d_in[0];
    const float* wu = (const float*)d_in[1];  // already masked in setup
    const float* wd = (const float*)d_in[2];  // masks d_in[3]/d_in[4] redundant

    // workspace layout (bf16 as u16): x | W_up | W_down | h   (226.5 MB)
    u16* xb  = (u16*)d_ws;
    u16* wub = xb  + (size_t)T * DIN;
    u16* wdb = wub + (size_t)DFF * DIN;
    u16* hb  = wdb + (size_t)DM * DFF;

    // single fused convert launch (counts in float4 units)
    const int n4x  = T * DIN / 4;     // 12,582,912
    const int n4wu = DFF * DIN / 4;   //  6,291,456
    const int n4wd = DM * DFF / 4;    //  1,048,576
    cvt3_kernel<<<8192, 256, 0, stream>>>(x, xb, n4x, wu, wub, n4wu, wd, wdb, n4wd);

    // GEMM1 + fused exact GELU: h[T,DFF] = gelu(x @ W_up^T), bf16 out
    dim3 g1(DFF / 256, T / 256);   // (16, 32) = 512 wgs, 1 block/CU
    gemm256<true, u16><<<g1, 512, 0, stream>>>(xb, wub, hb, DIN, DIN, DIN, DFF);

    // GEMM2: out = h @ W_down^T, f32 direct
    dim3 g2(DM / 256, T / 256);    // (4, 32) = 128 wgs
    gemm256<false, float><<<g2, 512, 0, stream>>>(hb, wdb, (float*)d_out,
                                                  DFF, DFF, DFF, DM);
}

// Round 3
// 888.930 us; speedup vs baseline: 1.0744x; 1.0744x over previous
//
#include <hip/hip_runtime.h>
#include <cstdint>
#include <cstddef>

typedef unsigned short u16;
typedef __attribute__((ext_vector_type(8))) short  bf16x8;  // 8 bf16 = 4 VGPRs
typedef __attribute__((ext_vector_type(4))) float  f32x4;   // MFMA C/D frag
typedef __attribute__((ext_vector_type(4))) unsigned short u16x4;

// ---------- helpers ----------
__device__ __forceinline__ u16 f2bf(float f) {
    unsigned u = __float_as_uint(f);
    unsigned r = (u + 0x7FFFu + ((u >> 16) & 1u)) >> 16;
    return (u16)r;
}

__device__ __forceinline__ void async_lds16(const u16* g, u16* l) {
    __builtin_amdgcn_global_load_lds(
        (const __attribute__((address_space(1))) unsigned int*)g,
        (__attribute__((address_space(3))) unsigned int*)l,
        16, 0, 0);
}

// ---------- f32 -> bf16 convert, dense 16B-in/8B-out per lane, grid-stride ----------
__global__ __launch_bounds__(256) void cvt3_kernel(const float* __restrict__ s0, u16* __restrict__ d0, int n0,
                                                   const float* __restrict__ s1, u16* __restrict__ d1, int n1,
                                                   const float* __restrict__ s2, u16* __restrict__ d2, int n2) {
    const int total = n0 + n1 + n2;
    for (int i = blockIdx.x * 256 + threadIdx.x; i < total; i += gridDim.x * 256) {
        const float* s; u16* d; int j = i;
        if (j < n0)            { s = s0; d = d0; }
        else if (j < n0 + n1)  { s = s1; d = d1; j -= n0; }
        else                   { s = s2; d = d2; j -= n0 + n1; }
        float4 a = ((const float4*)s)[j];
        u16x4 o;
        o[0] = f2bf(a.x); o[1] = f2bf(a.y); o[2] = f2bf(a.z); o[3] = f2bf(a.w);
        ((u16x4*)d)[j] = o;
    }
}

// ---------- 256xBN, KSTEP=32, 4-deep ring, 1-barrier/step bf16 GEMM, C = A @ B^T ----
// R3: fine-grained pipeline. Per K-step (32):
//   stage(t+3) | read ph1-A | [MFMA ph0 covers reads] | lgkm0 | vmcnt(2SL) | barrier
//   | read ph0(t+1)+B(t+1) | [MFMA ph1 covers reads] | lgkm0
// Race-freedom (all waves, max skew):
//  - stage(t+4)@top of t+1 overwrites buf[t&3]; every wave's reads of buf[t&3]
//    (ph1-A @top of t, B @end of t-1, ph0-A @end of t-1) are DRAINED (lgkm0)
//    before that wave arrives at bar(t); writer issues after passing bar(t). ✓
//  - reads of tile t+1 (issued after bar(t)) follow every wave's vmcnt(2SL)
//    (t+1's loads retired, FIFO) + barrier ⇒ data visible. ✓
//  - tail: stage of tiles >= NT wraps (NT%4==0 -> same buffer ring slot), writes
//    garbage into a never-again-read buffer; vmem ledger stays uniform.
//  - post-loop vmcnt(0): don't leave LDS-DMA in flight into a successor wg's LDS.
#define KSTEP 32
#define ASZ (256 * KSTEP)

template<bool GELU, typename OutT, int BN>
__global__ __launch_bounds__(512, 2) void gemm_ffn(const u16* __restrict__ A,
                                                   const u16* __restrict__ B,
                                                   OutT* __restrict__ C,
                                                   int K, int lda, int ldb, int ldc) {
    constexpr int NI = BN / 64;            // B frags per wave (4 or 2)
    constexpr int SL = (BN == 256) ? 4 : 3; // stage loads per thread per step
    __shared__ __align__(16) u16 sA[4][ASZ];          // 64 KB
    __shared__ __align__(16) u16 sB[4][BN * KSTEP];   // 64 or 32 KB

    const int tid  = threadIdx.x;
    const int wave = tid >> 6;
    const int lane = tid & 63;
    const int quad = lane >> 4;
    const int r16  = lane & 15;

    // XCD-chunked bijective swizzle (T1); nwg % 8 == 0 for all our launches
    const int nwg = gridDim.x * gridDim.y;
    int lin = blockIdx.y * gridDim.x + blockIdx.x;
    lin = (lin & 7) * (nwg >> 3) + (lin >> 3);
    const int n0 = (lin % gridDim.x) * BN;
    const int m0 = (lin / gridDim.x) * 256;

    const int wm = (wave >> 2) * 128;          // 2 waves tile M
    const int wn = (wave & 3) * (BN / 4);      // 4 waves tile N

    // staging map: per issue, 8 waves x 16 rows x 64B; lane -> row (lane>>2),
    // granule (lane&3); XOR-swizzle applied on the GLOBAL granule (involution).
    const int sr0 = wave * 16 + (lane >> 2);                 // issue-0 row (0..127)
    const int gc0 = (((lane & 3) ^ ((sr0 >> 1) & 3))) * 8;   // same for row+128 (128%4==0)
    const int ldsw = wave * 512;                             // wave*16 rows * 32 elems

    const u16* gA0 = A + (size_t)(m0 + sr0) * lda + gc0;
    const u16* gA1 = gA0 + (size_t)128 * lda;
    const u16* gB0 = B + (size_t)(n0 + sr0) * ldb + gc0;
    const u16* gB1 = gB0 + (size_t)128 * ldb;   // unused when BN==128

#define STAGE(kt, tb) { const int ko_ = (kt) * KSTEP; \
        async_lds16(gA0 + ko_, &sA[tb][ldsw]); \
        async_lds16(gA1 + ko_, &sA[tb][4096 + ldsw]); \
        async_lds16(gB0 + ko_, &sB[tb][ldsw]); \
        if constexpr (BN == 256) async_lds16(gB1 + ko_, &sB[tb][4096 + ldsw]); }

    // loop-invariant per-lane fragment offsets into a [rows][32] step block
    int oA[8], oB[NI];
#pragma unroll
    for (int i = 0; i < 8; i++) {
        int ra = wm + i * 16 + r16;
        oA[i] = ra * 32 + ((quad ^ ((ra >> 1) & 3)) << 3);
    }
#pragma unroll
    for (int i = 0; i < NI; i++) {
        int rb = wn + i * 16 + r16;
        oB[i] = rb * 32 + ((quad ^ ((rb >> 1) & 3)) << 3);
    }

    f32x4 acc[8][NI] = {};
    const int NT = K / KSTEP;   // 192 (GEMM1) / 128 (GEMM2); both % 4 == 0

#define LGKM0 asm volatile("s_waitcnt lgkmcnt(0)" ::: "memory"); __builtin_amdgcn_sched_barrier(0)
#define SBAR  __builtin_amdgcn_sched_barrier(0)
#define VMCNT_STEADY if constexpr (BN == 256) { asm volatile("s_waitcnt vmcnt(8)" ::: "memory"); } \
                     else { asm volatile("s_waitcnt vmcnt(6)" ::: "memory"); }
#define MFMA_Q(mb, AF, BF) \
    __builtin_amdgcn_s_setprio(1); \
    _Pragma("unroll") \
    for (int mi_ = 0; mi_ < 4; mi_++) \
        _Pragma("unroll") \
        for (int ni_ = 0; ni_ < NI; ni_++) \
            acc[(mb) + mi_][ni_] = __builtin_amdgcn_mfma_f32_16x16x32_bf16( \
                AF[mi_], BF[ni_], acc[(mb) + mi_][ni_], 0, 0, 0); \
    __builtin_amdgcn_s_setprio(0); \
    __builtin_amdgcn_sched_barrier(0)

    bf16x8 afA[4], afB[4], bfA[NI], bfB[NI];

    // prologue: tiles 0,1,2 staged; wait tile 0; read its ph0 frags
    STAGE(0, 0); STAGE(1, 1); STAGE(2, 2);
    VMCNT_STEADY;                       // retires tile 0's SL loads (FIFO)
    __builtin_amdgcn_s_barrier();
    SBAR;
#pragma unroll
    for (int i = 0; i < 4; i++)  afA[i] = *(const bf16x8*)&sA[0][oA[i]];
#pragma unroll
    for (int i = 0; i < NI; i++) bfA[i] = *(const bf16x8*)&sB[0][oB[i]];
    LGKM0;

    // one K-step; c = t&3, n1 = (t+1)&3, t3 = (t+3)&3; BC = B(t) regs, BNx = B(t+1) regs
#define STEP(T, c, n1, t3, BC, BNx) { \
        int kt3_ = (T) + 3; if (kt3_ >= NT) kt3_ -= NT; \
        STAGE(kt3_, t3); \
        _Pragma("unroll") \
        for (int i = 0; i < 4; i++) afB[i] = *(const bf16x8*)&sA[c][oA[4 + i]]; \
        SBAR; \
        MFMA_Q(0, afA, BC); \
        LGKM0; \
        VMCNT_STEADY; \
        __builtin_amdgcn_s_barrier(); \
        SBAR; \
        _Pragma("unroll") \
        for (int i = 0; i < 4; i++)  afA[i] = *(const bf16x8*)&sA[n1][oA[i]]; \
        _Pragma("unroll") \
        for (int i = 0; i < NI; i++) BNx[i] = *(const bf16x8*)&sB[n1][oB[i]]; \
        SBAR; \
        MFMA_Q(4, afB, BC); \
        LGKM0; \
    }

    for (int t = 0; t < NT; t += 4) {
        STEP(t + 0, 0, 1, 3, bfA, bfB);
        STEP(t + 1, 1, 2, 0, bfB, bfA);
        STEP(t + 2, 2, 3, 1, bfA, bfB);
        STEP(t + 3, 3, 0, 2, bfB, bfA);
    }
    asm volatile("s_waitcnt vmcnt(0)" ::: "memory");  // wg-teardown LDS-DMA safety

    // epilogue: C/D layout col = lane&15, row = quad*4 + reg  [m89-verified]
#pragma unroll
    for (int mi = 0; mi < 8; mi++) {
#pragma unroll
        for (int r = 0; r < 4; r++) {
            size_t rowoff = (size_t)(m0 + wm + mi * 16 + quad * 4 + r) * ldc;
#pragma unroll
            for (int ni = 0; ni < NI; ni++) {
                int col = n0 + wn + ni * 16 + r16;
                float v = acc[mi][ni][r];
                if constexpr (GELU)
                    v = 0.5f * v * (1.0f + erff(v * 0.70710678118654752f));
                if constexpr (sizeof(OutT) == 2)
                    ((u16*)C)[rowoff + col] = f2bf(v);
                else
                    ((float*)C)[rowoff + col] = v;
            }
        }
    }
}

// ---------- launch ----------
extern "C" void kernel_launch(void* const* d_in, const int* in_sizes, int n_in,
                              void* d_out, int out_size, void* d_ws, size_t ws_size,
                              hipStream_t stream) {
    const int T   = 8192;
    const int DIN = 6144;
    const int DFF = 4096;
    const int DM  = 1024;

    const float* x  = (const float*)d_in[0];
    const float* wu = (const float*)d_in[1];  // already masked in setup
    const float* wd = (const float*)d_in[2];  // masks d_in[3]/d_in[4] redundant

    // workspace layout (bf16 as u16): x | W_up | W_down | h
    u16* xb  = (u16*)d_ws;
    u16* wub = xb  + (size_t)T * DIN;
    u16* wdb = wub + (size_t)DFF * DIN;
    u16* hb  = wdb + (size_t)DM * DFF;

    // single fused convert launch (counts in float4 units)
    const int n4x  = T * DIN / 4;
    const int n4wu = DFF * DIN / 4;
    const int n4wd = DM * DFF / 4;
    cvt3_kernel<<<8192, 256, 0, stream>>>(x, xb, n4x, wu, wub, n4wu, wd, wdb, n4wd);

    // GEMM1 + fused exact GELU: h[T,DFF] = gelu(x @ W_up^T), bf16 out; 256x256 tiles
    dim3 g1(DFF / 256, T / 256);   // (16, 32) = 512 wgs, 2 clean rounds
    gemm_ffn<true, u16, 256><<<g1, 512, 0, stream>>>(xb, wub, hb, DIN, DIN, DIN, DFF);

    // GEMM2: out = h @ W_down^T, f32 direct; 256x128 tiles -> full-machine grid
    dim3 g2(DM / 128, T / 256);    // (8, 32) = 256 wgs, 1 round on 256 CUs
    gemm_ffn<false, float, 128><<<g2, 512, 0, stream>>>(hb, wdb, (float*)d_out,
                                                        DFF, DFF, DFF, DM);
}